// Round 20
// baseline (411.641 us; speedup 1.0000x reference)
//
#include <hip/hip_runtime.h>
#include <hip/hip_bf16.h>
#include <stdint.h>
#include <stddef.h>

typedef _Float16 half2_t __attribute__((ext_vector_type(2)));
typedef _Float16 f16x8 __attribute__((ext_vector_type(8)));
typedef float f32x4 __attribute__((ext_vector_type(4)));

// ---------------- param_net stage 1: partial h = X @ W1 (K-split) ----------
// r15: W1+X staged in LDS, acc[16] blocking (was 111us reg-starved; now ~8us).
__global__ __launch_bounds__(256, 2) void k_paramnet1(
    const float* __restrict__ X, const float* __restrict__ W1,
    float* __restrict__ hpart) {
  const int ks = blockIdx.x;        // K-slice of 128
  const int b0 = blockIdx.y * 32;   // row group of 32
  const int t = threadIdx.x;

  __shared__ float sw[128 * 128];   // W1 slice [k][j]  (64 KB)
  __shared__ float sx[32 * 128];    // X slice  [row][k] (16 KB)

  {  // W1 slice is contiguous memory: W1 + ks*16384
    const float4* src = (const float4*)(W1 + (size_t)ks * 16384);
    float4* dst = (float4*)sw;
#pragma unroll
    for (int i = 0; i < 16; ++i) dst[t + i * 256] = src[t + i * 256];
  }
  {  // X rows b0..b0+31, cols ks*128..+128; 8 threads x 4 float4 per row
    const int r = t >> 3, c = t & 7;
    const float4* srcr = (const float4*)(X + (size_t)(b0 + r) * 4096 + ks * 128);
    float4* dstr = (float4*)(sx + r * 128);
#pragma unroll
    for (int i = 0; i < 4; ++i) dstr[c + i * 8] = srcr[c + i * 8];
  }
  __syncthreads();

  const int j = t & 127;
  const int rh = t >> 7;  // 0/1: thread owns slice-rows rh, rh+2, ..., rh+30

  float acc[16];
#pragma unroll
  for (int i = 0; i < 16; ++i) acc[i] = 0.f;

  for (int k4 = 0; k4 < 32; ++k4) {
    const float w0 = sw[(k4 * 4 + 0) * 128 + j];
    const float w1v = sw[(k4 * 4 + 1) * 128 + j];
    const float w2 = sw[(k4 * 4 + 2) * 128 + j];
    const float w3 = sw[(k4 * 4 + 3) * 128 + j];
#pragma unroll
    for (int i = 0; i < 16; ++i) {
      const float4 xv = *(const float4*)(sx + (rh + 2 * i) * 128 + k4 * 4);
      acc[i] = fmaf(xv.x, w0,
               fmaf(xv.y, w1v,
               fmaf(xv.z, w2,
               fmaf(xv.w, w3, acc[i]))));
    }
  }
#pragma unroll
  for (int i = 0; i < 16; ++i) {
    const int row = b0 + rh + 2 * i;
    hpart[((size_t)ks * 512 + row) * 128 + j] = acc[i];
  }
}

// ---------------- param_net stage 2: reduce partials + bias + relu ---------
__global__ __launch_bounds__(256) void k_paramnet2(
    const float* __restrict__ hpart, const float* __restrict__ b1,
    float* __restrict__ h) {
  const int idx = blockIdx.x * 256 + threadIdx.x;
  float s = b1[idx & 127];
#pragma unroll
  for (int ks = 0; ks < 32; ++ks) s += hpart[(size_t)ks * 65536 + idx];
  h[idx] = fmaxf(s, 0.f);
}

// ---------------- params = h @ W2 + b2 -> sigmoids -> state + stat partials
// Round 17: was 256 blocks x 2 b's = 1 block/CU = 1 wave/SIMD (worst latency
// hiding). Now 512 blocks x 1 b = 2 blocks/CU, half the per-block serial
// work, same total loads.
__global__ __launch_bounds__(256) void k_params_state(
    const float* __restrict__ h, const float* __restrict__ W2,
    const float* __restrict__ b2, const float* __restrict__ X,
    float* __restrict__ betaW, float* __restrict__ sigmaW,
    float* __restrict__ gammaW, float* __restrict__ S0W,
    float* __restrict__ E0W, float* __restrict__ I0W,
    float* __restrict__ stats) {
  const int b = blockIdx.x;
  const int t = threadIdx.x;
  const float* h0 = h + (size_t)b * 128;
  float a0 = b2[t], a1 = b2[256 + t], a2 = b2[512 + t], a3 = b2[768 + t];
#pragma unroll 4
  for (int k = 0; k < 128; ++k) {
    const float* wr = W2 + (size_t)k * 1024;
    const float hv = h0[k];
    a0 = fmaf(hv, wr[t], a0);
    a1 = fmaf(hv, wr[256 + t], a1);
    a2 = fmaf(hv, wr[512 + t], a2);
    a3 = fmaf(hv, wr[768 + t], a3);
  }
  const float beta = 3.f / (1.f + __expf(-a0));
  const float sig  = 1.f / (1.f + __expf(-a1));
  const float gam  = 1.f / (1.f + __expf(-a2));
  const float e0r  = 5.f / (1.f + __expf(-a3));
  const int base = b * 256 + t;
  const float I0 = fmaxf(X[(size_t)b * 4096 + 15 * 256 + t], 1e-6f);
  const float E0 = I0 * e0r;
  const float S0 = fmaxf(1.f - E0 - I0, 0.01f);
  betaW[base] = beta; sigmaW[base] = sig; gammaW[base] = gam;
  S0W[base] = S0; E0W[base] = E0; I0W[base] = I0;
  atomicAdd(stats + t, beta);
  atomicAdd(stats + 256 + t, sig);
  atomicAdd(stats + 512 + t, gam);
}

// ---------------- transpose M2 -> M2T[n][m][k] f16 + fused mobility1 -------
// Round 17: M2 staging loads vectorized float4 (16B/lane, 4x fewer load
// instructions; was 128 scalar dword loads/thread at 256KB stride).
__global__ __launch_bounds__(256) void k_cvtM2(
    const float* __restrict__ M2, _Float16* __restrict__ M2T,
    const float* __restrict__ cnn, const float* __restrict__ M1,
    const float* __restrict__ mb1, _Float16* __restrict__ hmf) {
  const int n = blockIdx.x, t = threadIdx.x;

  {  // fused mobility stage 1 (rows 2n, 2n+1)
    const int b = 2 * n + (t >> 7);
    const int j = t & 127;
    const float* cr = cnn + b * 64;
    float a = mb1[j];
#pragma unroll
    for (int k = 0; k < 64; ++k) a = fmaf(cr[k], M1[k * 128 + j], a);
    hmf[n * 256 + t] = (_Float16)fmaxf(a, 0.f);
  }

  __shared__ _Float16 sm[128 * 256];  // 64 KB
  {  // stage M2 cols n*256..+255, rows 0..127: float4 loads, 4 rows/iter
    const int kk = t >> 6, c4 = t & 63;
#pragma unroll 8
    for (int i = 0; i < 32; ++i) {
      const int row = i * 4 + kk;
      const float4 v =
          *(const float4*)(M2 + (size_t)row * 65536 + n * 256 + c4 * 4);
      sm[row * 256 + c4 * 4 + 0] = (_Float16)v.x;
      sm[row * 256 + c4 * 4 + 1] = (_Float16)v.y;
      sm[row * 256 + c4 * 4 + 2] = (_Float16)v.z;
      sm[row * 256 + c4 * 4 + 3] = (_Float16)v.w;
    }
  }
  __syncthreads();
  half2_t col[64];
#pragma unroll 16
  for (int k2 = 0; k2 < 64; ++k2)
    col[k2] = half2_t{sm[(2 * k2) * 256 + t], sm[(2 * k2 + 1) * 256 + t]};
  uint4* dst = (uint4*)(M2T + ((size_t)n * 256 + t) * 128);
  const uint4* s4 = (const uint4*)col;
#pragma unroll
  for (int i = 0; i < 16; ++i) dst[i] = s4[i];
}

// ---------------- mobility stage 2: MFMA GEMM + in-register softmax --------
__global__ __launch_bounds__(512, 2) void k_mobility2(
    const _Float16* __restrict__ hmf, const _Float16* __restrict__ M2T,
    const float* __restrict__ mb2, _Float16* __restrict__ PiF,
    float* __restrict__ pimpart) {
  const int n = blockIdx.x;
  const int pass = blockIdx.y;
  const int tid = threadIdx.x;
  const int wave = tid >> 6;
  const int lane = tid & 63;
  const int q = lane >> 4;
  const int c = lane & 15;

  __shared__ _Float16 sm[8][16 * 256];  // 64 KB, wave-private slots

  const _Float16* Bbase = M2T + (size_t)n * 32768 + (size_t)c * 128 + q * 8;
  const float* mbp = mb2 + n * 256 + c;

  const int bt0 = wave * 4 + pass * 2;
  f32x4 C0[16], C1[16];
#pragma unroll
  for (int nb = 0; nb < 16; ++nb) {
    const float mbv = mbp[nb * 16];
    C0[nb] = f32x4{mbv, mbv, mbv, mbv};
    C1[nb] = C0[nb];
  }
  const _Float16* A0 = hmf + (size_t)(bt0 * 16 + c) * 128 + q * 8;
  const _Float16* A1 = A0 + 16 * 128;
#pragma unroll
  for (int ks = 0; ks < 4; ++ks) {
    const f16x8 Af0 = *(const f16x8*)(A0 + ks * 32);
    const f16x8 Af1 = *(const f16x8*)(A1 + ks * 32);
#pragma unroll
    for (int nb = 0; nb < 16; ++nb) {
      const f16x8 Bf = *(const f16x8*)(Bbase + nb * 2048 + ks * 32);
      C0[nb] = __builtin_amdgcn_mfma_f32_16x16x32_f16(Af0, Bf, C0[nb], 0, 0, 0);
      C1[nb] = __builtin_amdgcn_mfma_f32_16x16x32_f16(Af1, Bf, C1[nb], 0, 0, 0);
    }
  }

  float colsum[16];
#pragma unroll
  for (int nb = 0; nb < 16; ++nb) colsum[nb] = 0.f;

#pragma unroll
  for (int half = 0; half < 2; ++half) {
    f32x4* C = half ? C1 : C0;
    const int bt = bt0 + half;
    float mx[4], sum[4];
#pragma unroll
    for (int r = 0; r < 4; ++r) mx[r] = C[0][r];
#pragma unroll
    for (int nb = 1; nb < 16; ++nb)
#pragma unroll
      for (int r = 0; r < 4; ++r) mx[r] = fmaxf(mx[r], C[nb][r]);
#pragma unroll
    for (int r = 0; r < 4; ++r) {
      mx[r] = fmaxf(mx[r], __shfl_xor(mx[r], 1, 16));
      mx[r] = fmaxf(mx[r], __shfl_xor(mx[r], 2, 16));
      mx[r] = fmaxf(mx[r], __shfl_xor(mx[r], 4, 16));
      mx[r] = fmaxf(mx[r], __shfl_xor(mx[r], 8, 16));
      sum[r] = 0.f;
    }
#pragma unroll
    for (int nb = 0; nb < 16; ++nb)
#pragma unroll
      for (int r = 0; r < 4; ++r) {
        const float e = __expf(C[nb][r] - mx[r]);
        C[nb][r] = e;
        sum[r] += e;
      }
#pragma unroll
    for (int r = 0; r < 4; ++r) {
      sum[r] += __shfl_xor(sum[r], 1, 16);
      sum[r] += __shfl_xor(sum[r], 2, 16);
      sum[r] += __shfl_xor(sum[r], 4, 16);
      sum[r] += __shfl_xor(sum[r], 8, 16);
      sum[r] = 1.f / sum[r];
    }
    _Float16* slot = sm[wave];
#pragma unroll
    for (int nb = 0; nb < 16; ++nb) {
#pragma unroll
      for (int r = 0; r < 4; ++r) {
        const float v = C[nb][r] * sum[r];
        colsum[nb] += v;
        slot[(q * 4 + r) * 256 + nb * 16 + c] = (_Float16)v;
      }
    }
    const int l2 = lane & 31, rh = lane >> 5;
    _Float16* Pg = PiF + ((size_t)(bt * 16) * 256 + n) * 256;
#pragma unroll
    for (int i = 0; i < 8; ++i) {
      const int row = i * 2 + rh;
      const uint4 v = *(const uint4*)(slot + row * 256 + l2 * 8);
      *(uint4*)(Pg + (size_t)row * 65536 + l2 * 8) = v;
    }
  }
#pragma unroll
  for (int nb = 0; nb < 16; ++nb) {
    colsum[nb] += __shfl_xor(colsum[nb], 16);
    colsum[nb] += __shfl_xor(colsum[nb], 32);
  }
  if (lane < 16) {
    float* pp = pimpart + n * 256 + lane;
#pragma unroll
    for (int nb = 0; nb < 16; ++nb) atomicAdd(pp + nb * 16, colsum[nb]);
  }
}

// ---------------- SEIR RK4 simulation — r8 structure, 4-WAY TEMPORAL SPLIT -
// Round 17 data: gather G=19.7us, per-week W=10.8us (from 1-part vs 2-part).
// 4 parts of 3 weeks (~52us each) drop the top-5 visibility threshold from
// 84 to 52us — any of {pn2, params_state, cvtM2, mobility2} >=52us must
// surface. One-round diagnostic; merge back next round.
__global__ __launch_bounds__(256, 2) void k_sim_part(
    const _Float16* __restrict__ PiF, const float* __restrict__ betaW,
    const float* __restrict__ sigmaW, const float* __restrict__ gammaW,
    float* __restrict__ SW, float* __restrict__ EW, float* __restrict__ IW,
    const float* __restrict__ stats, const float* __restrict__ pimpart,
    float* __restrict__ out, int wk0, int nwk, int do_finalize) {
  const int b = blockIdx.x;
  const int tid = threadIdx.x;

  if (do_finalize) {  // fused k_finalize: means of stats + Pi (part a only)
    const int g = b * 256 + tid;
    if (g < 66304) {
      const float inv = 1.f / 512.f;
      if (g < 768) out[3145728 + g] = stats[g] * inv;
      else out[3146496 + (g - 768)] = pimpart[g - 768] * inv;
    }
  }

  const int w = tid >> 6, lane = tid & 63;
  const int q = lane >> 4, c = lane & 15;
  const int mown = (4 * w + q) * 16 + c;

  __shared__ __align__(16) _Float16 Ib[2][256];

  f16x8 Bf[4][8];
  {
    const _Float16* P = PiF + (size_t)b * 65536 + (size_t)(q * 8) * 256 + c;
#pragma unroll
    for (int i = 0; i < 4; ++i) {
#pragma unroll
      for (int t = 0; t < 8; ++t) {
        const _Float16* src = P + (size_t)(t * 32) * 256 + (4 * w + i) * 16;
        f16x8 v;
#pragma unroll
        for (int j = 0; j < 8; ++j) v[j] = src[(size_t)j * 256];
        Bf[i][t] = v;
      }
    }
  }

  const int base = b * 256 + mown;
  const float bet = betaW[base], sig = sigmaW[base], gam = gammaW[base];
  float S = SW[base], E = EW[base], I = IW[base];

  int p = 0;
  auto grads = [&](float Ss, float Es, float Is, float& dS, float& dE, float& dI) {
    Ib[p][mown] = (_Float16)Is;
    __syncthreads();
    const f16x8* ia = (const f16x8*)Ib[p];
    p ^= 1;
    f32x4 C[4];
#pragma unroll
    for (int i = 0; i < 4; ++i) C[i] = f32x4{0.f, 0.f, 0.f, 0.f};
#pragma unroll
    for (int t = 0; t < 8; ++t) {
      const f16x8 A = ia[t * 4 + q];  // element offset t*32 + q*8
#pragma unroll
      for (int i = 0; i < 4; ++i)
        C[i] = __builtin_amdgcn_mfma_f32_16x16x32_f16(A, Bf[i][t], C[i], 0, 0, 0);
    }
    // force for m = (4w+q)*16+c lives in C[q] (all rows identical)
    const float force = (q & 2) ? ((q & 1) ? C[3][0] : C[2][0])
                                : ((q & 1) ? C[1][0] : C[0][0]);
    const float ninf = bet * Ss * force;
    const float sE = sig * Es;
    dS = -ninf;
    dE = ninf - sE;
    dI = sE - gam * Is;
  };

  float* outI = out + (size_t)b * (12 * 256) + mown;
  float* outE = outI + 1572864;
  const float c6 = 0.25f / 6.f;

  for (int wk = wk0; wk < wk0 + nwk; ++wk) {
    for (int st = 0; st < 4; ++st) {
      float d1S, d1E, d1I, d2S, d2E, d2I, d3S, d3E, d3I, d4S, d4E, d4I;
      grads(S, E, I, d1S, d1E, d1I);
      grads(S + 0.125f * d1S, E + 0.125f * d1E, I + 0.125f * d1I, d2S, d2E, d2I);
      grads(S + 0.125f * d2S, E + 0.125f * d2E, I + 0.125f * d2I, d3S, d3E, d3I);
      grads(S + 0.25f * d3S, E + 0.25f * d3E, I + 0.25f * d3I, d4S, d4E, d4I);
      S = fminf(fmaxf(S + c6 * (d1S + 2.f * d2S + 2.f * d3S + d4S), 0.f), 1.f);
      E = fminf(fmaxf(E + c6 * (d1E + 2.f * d2E + 2.f * d3E + d4E), 0.f), 1.f);
      I = fminf(fmaxf(I + c6 * (d1I + 2.f * d2I + 2.f * d3I + d4I), 0.f), 1.f);
    }
    outI[wk * 256] = I;
    outE[wk * 256] = E;
  }

  // persist exact f32 state for the next part (harmless in the last part)
  SW[base] = S; EW[base] = E; IW[base] = I;
}

// ---------------- launch ---------------------------------------------------
extern "C" void kernel_launch(void* const* d_in, const int* in_sizes, int n_in,
                              void* d_out, int out_size, void* d_ws, size_t ws_size,
                              hipStream_t stream) {
  const float* x_hist = (const float*)d_in[0];
  const float* cnn    = (const float*)d_in[1];
  const float* W1     = (const float*)d_in[2];
  const float* b1     = (const float*)d_in[3];
  const float* W2     = (const float*)d_in[4];
  const float* b2     = (const float*)d_in[5];
  const float* M1     = (const float*)d_in[6];
  const float* mb1    = (const float*)d_in[7];
  const float* M2     = (const float*)d_in[8];
  const float* mb2    = (const float*)d_in[9];
  float* out = (float*)d_out;

  char* w = (char*)d_ws;
  _Float16* M2T     = (_Float16*)(w + 0);         // 16,777,216
  _Float16* hmf     = (_Float16*)(w + 16777216);  //    131,072
  float*    betaW   = (float*)(w + 16908288);     //    524,288 each
  float*    sigmaW  = (float*)(w + 17432576);
  float*    gammaW  = (float*)(w + 17956864);
  float*    S0W     = (float*)(w + 18481152);
  float*    E0W     = (float*)(w + 19005440);
  float*    I0W     = (float*)(w + 19529728);
  float*    pimpart = (float*)(w + 20054016);     //    262,144
  float*    stats   = (float*)(w + 20316160);     //      4,096 (768 used)
  _Float16* PiF     = (_Float16*)(w + 20320256);  // 67,108,864 (end 87.4MB)
  // hpart/h alias the PiF region (dead before k_mobility2 writes PiF)
  float*    hpart   = (float*)(w + 20320256);     //  8,388,608
  float*    h       = (float*)(w + 28708864);     //    262,144

  hipMemsetAsync(pimpart, 0, 266240, stream);  // pimpart + stats
  k_paramnet1<<<dim3(32, 16), 256, 0, stream>>>(x_hist, W1, hpart);
  k_paramnet2<<<256, 256, 0, stream>>>(hpart, b1, h);
  k_params_state<<<512, 256, 0, stream>>>(h, W2, b2, x_hist, betaW, sigmaW,
                                          gammaW, S0W, E0W, I0W, stats);
  k_cvtM2<<<256, 256, 0, stream>>>(M2, M2T, cnn, M1, mb1, hmf);
  k_mobility2<<<dim3(256, 2), 512, 0, stream>>>(hmf, M2T, mb2, PiF, pimpart);
  k_sim_part<<<512, 256, 0, stream>>>(PiF, betaW, sigmaW, gammaW, S0W, E0W,
                                      I0W, stats, pimpart, out, 0, 3, 1);
  k_sim_part<<<512, 256, 0, stream>>>(PiF, betaW, sigmaW, gammaW, S0W, E0W,
                                      I0W, stats, pimpart, out, 3, 3, 0);
  k_sim_part<<<512, 256, 0, stream>>>(PiF, betaW, sigmaW, gammaW, S0W, E0W,
                                      I0W, stats, pimpart, out, 6, 3, 0);
  k_sim_part<<<512, 256, 0, stream>>>(PiF, betaW, sigmaW, gammaW, S0W, E0W,
                                      I0W, stats, pimpart, out, 9, 3, 0);
}

// Round 21
// 378.189 us; speedup vs baseline: 1.0885x; 1.0885x over previous
//
#include <hip/hip_runtime.h>
#include <hip/hip_bf16.h>
#include <stdint.h>
#include <stddef.h>

typedef _Float16 half2_t __attribute__((ext_vector_type(2)));
typedef _Float16 f16x8 __attribute__((ext_vector_type(8)));
typedef float f32x4 __attribute__((ext_vector_type(4)));

// ---------------- param_net stage 1: partial h = X @ W1 (K-split) ----------
// r15: W1+X staged in LDS, acc[16] blocking (was 111us reg-starved; now ~8us).
__global__ __launch_bounds__(256, 2) void k_paramnet1(
    const float* __restrict__ X, const float* __restrict__ W1,
    float* __restrict__ hpart) {
  const int ks = blockIdx.x;        // K-slice of 128
  const int b0 = blockIdx.y * 32;   // row group of 32
  const int t = threadIdx.x;

  __shared__ float sw[128 * 128];   // W1 slice [k][j]  (64 KB)
  __shared__ float sx[32 * 128];    // X slice  [row][k] (16 KB)

  {  // W1 slice is contiguous memory: W1 + ks*16384
    const float4* src = (const float4*)(W1 + (size_t)ks * 16384);
    float4* dst = (float4*)sw;
#pragma unroll
    for (int i = 0; i < 16; ++i) dst[t + i * 256] = src[t + i * 256];
  }
  {  // X rows b0..b0+31, cols ks*128..+128; 8 threads x 4 float4 per row
    const int r = t >> 3, c = t & 7;
    const float4* srcr = (const float4*)(X + (size_t)(b0 + r) * 4096 + ks * 128);
    float4* dstr = (float4*)(sx + r * 128);
#pragma unroll
    for (int i = 0; i < 4; ++i) dstr[c + i * 8] = srcr[c + i * 8];
  }
  __syncthreads();

  const int j = t & 127;
  const int rh = t >> 7;  // 0/1: thread owns slice-rows rh, rh+2, ..., rh+30

  float acc[16];
#pragma unroll
  for (int i = 0; i < 16; ++i) acc[i] = 0.f;

  for (int k4 = 0; k4 < 32; ++k4) {
    const float w0 = sw[(k4 * 4 + 0) * 128 + j];
    const float w1v = sw[(k4 * 4 + 1) * 128 + j];
    const float w2 = sw[(k4 * 4 + 2) * 128 + j];
    const float w3 = sw[(k4 * 4 + 3) * 128 + j];
#pragma unroll
    for (int i = 0; i < 16; ++i) {
      const float4 xv = *(const float4*)(sx + (rh + 2 * i) * 128 + k4 * 4);
      acc[i] = fmaf(xv.x, w0,
               fmaf(xv.y, w1v,
               fmaf(xv.z, w2,
               fmaf(xv.w, w3, acc[i]))));
    }
  }
#pragma unroll
  for (int i = 0; i < 16; ++i) {
    const int row = b0 + rh + 2 * i;
    hpart[((size_t)ks * 512 + row) * 128 + j] = acc[i];
  }
}

// ---------------- param_net stage 2: reduce partials + bias + relu ---------
__global__ __launch_bounds__(256) void k_paramnet2(
    const float* __restrict__ hpart, const float* __restrict__ b1,
    float* __restrict__ h) {
  const int idx = blockIdx.x * 256 + threadIdx.x;
  float s = b1[idx & 127];
#pragma unroll
  for (int ks = 0; ks < 32; ++ks) s += hpart[(size_t)ks * 65536 + idx];
  h[idx] = fmaxf(s, 0.f);
}

// ---------------- params = h @ W2 + b2 -> sigmoids -> state + stat partials
// r17: 512 blocks x 1 b = 2 blocks/CU (was 1), half per-block serial work.
__global__ __launch_bounds__(256) void k_params_state(
    const float* __restrict__ h, const float* __restrict__ W2,
    const float* __restrict__ b2, const float* __restrict__ X,
    float* __restrict__ betaW, float* __restrict__ sigmaW,
    float* __restrict__ gammaW, float* __restrict__ S0W,
    float* __restrict__ E0W, float* __restrict__ I0W,
    float* __restrict__ stats) {
  const int b = blockIdx.x;
  const int t = threadIdx.x;
  const float* h0 = h + (size_t)b * 128;
  float a0 = b2[t], a1 = b2[256 + t], a2 = b2[512 + t], a3 = b2[768 + t];
#pragma unroll 4
  for (int k = 0; k < 128; ++k) {
    const float* wr = W2 + (size_t)k * 1024;
    const float hv = h0[k];
    a0 = fmaf(hv, wr[t], a0);
    a1 = fmaf(hv, wr[256 + t], a1);
    a2 = fmaf(hv, wr[512 + t], a2);
    a3 = fmaf(hv, wr[768 + t], a3);
  }
  const float beta = 3.f / (1.f + __expf(-a0));
  const float sig  = 1.f / (1.f + __expf(-a1));
  const float gam  = 1.f / (1.f + __expf(-a2));
  const float e0r  = 5.f / (1.f + __expf(-a3));
  const int base = b * 256 + t;
  const float I0 = fmaxf(X[(size_t)b * 4096 + 15 * 256 + t], 1e-6f);
  const float E0 = I0 * e0r;
  const float S0 = fmaxf(1.f - E0 - I0, 0.01f);
  betaW[base] = beta; sigmaW[base] = sig; gammaW[base] = gam;
  S0W[base] = S0; E0W[base] = E0; I0W[base] = I0;
  atomicAdd(stats + t, beta);
  atomicAdd(stats + 256 + t, sig);
  atomicAdd(stats + 512 + t, gam);
}

// ---------------- transpose M2 -> M2T[n][m][k] f16 + fused mobility1 -------
// r17: M2 staging loads vectorized float4 (16B/lane).
__global__ __launch_bounds__(256) void k_cvtM2(
    const float* __restrict__ M2, _Float16* __restrict__ M2T,
    const float* __restrict__ cnn, const float* __restrict__ M1,
    const float* __restrict__ mb1, _Float16* __restrict__ hmf) {
  const int n = blockIdx.x, t = threadIdx.x;

  {  // fused mobility stage 1 (rows 2n, 2n+1)
    const int b = 2 * n + (t >> 7);
    const int j = t & 127;
    const float* cr = cnn + b * 64;
    float a = mb1[j];
#pragma unroll
    for (int k = 0; k < 64; ++k) a = fmaf(cr[k], M1[k * 128 + j], a);
    hmf[n * 256 + t] = (_Float16)fmaxf(a, 0.f);
  }

  __shared__ _Float16 sm[128 * 256];  // 64 KB
  {  // stage M2 cols n*256..+255, rows 0..127: float4 loads, 4 rows/iter
    const int kk = t >> 6, c4 = t & 63;
#pragma unroll 8
    for (int i = 0; i < 32; ++i) {
      const int row = i * 4 + kk;
      const float4 v =
          *(const float4*)(M2 + (size_t)row * 65536 + n * 256 + c4 * 4);
      sm[row * 256 + c4 * 4 + 0] = (_Float16)v.x;
      sm[row * 256 + c4 * 4 + 1] = (_Float16)v.y;
      sm[row * 256 + c4 * 4 + 2] = (_Float16)v.z;
      sm[row * 256 + c4 * 4 + 3] = (_Float16)v.w;
    }
  }
  __syncthreads();
  half2_t col[64];
#pragma unroll 16
  for (int k2 = 0; k2 < 64; ++k2)
    col[k2] = half2_t{sm[(2 * k2) * 256 + t], sm[(2 * k2 + 1) * 256 + t]};
  uint4* dst = (uint4*)(M2T + ((size_t)n * 256 + t) * 128);
  const uint4* s4 = (const uint4*)col;
#pragma unroll
  for (int i = 0; i < 16; ++i) dst[i] = s4[i];
}

// ---------------- mobility stage 2: MFMA GEMM + in-register softmax --------
// Round 20 counters (64.6us): nothing saturated (MFMA 5%, VALU 16%, HBM 30%)
// but SQ_LDS_BANK_CONFLICT=2^20 (4-way on slot b16 stores) and WRITE_SIZE
// 111.6MB vs ~68 expected (= ~44MB of atomic dirty-line flushes from 1M
// pimpart atomicAdds, 16 waves hammering the same 1KB per n). Fixes:
// (1) nb^q XOR-swizzle on slot stores (inverse on b128 reads) -> 0 conflicts;
// (2) block-level colsum reduction via LDS (reuse slot after barrier) ->
//     256 atomics/block instead of 2048.
__global__ __launch_bounds__(512, 2) void k_mobility2(
    const _Float16* __restrict__ hmf, const _Float16* __restrict__ M2T,
    const float* __restrict__ mb2, _Float16* __restrict__ PiF,
    float* __restrict__ pimpart) {
  const int n = blockIdx.x;
  const int pass = blockIdx.y;
  const int tid = threadIdx.x;
  const int wave = tid >> 6;
  const int lane = tid & 63;
  const int q = lane >> 4;
  const int c = lane & 15;

  __shared__ _Float16 sm[8][16 * 256];  // 64 KB, wave-private slots

  const _Float16* Bbase = M2T + (size_t)n * 32768 + (size_t)c * 128 + q * 8;
  const float* mbp = mb2 + n * 256 + c;

  const int bt0 = wave * 4 + pass * 2;
  f32x4 C0[16], C1[16];
#pragma unroll
  for (int nb = 0; nb < 16; ++nb) {
    const float mbv = mbp[nb * 16];
    C0[nb] = f32x4{mbv, mbv, mbv, mbv};
    C1[nb] = C0[nb];
  }
  const _Float16* A0 = hmf + (size_t)(bt0 * 16 + c) * 128 + q * 8;
  const _Float16* A1 = A0 + 16 * 128;
#pragma unroll
  for (int ks = 0; ks < 4; ++ks) {
    const f16x8 Af0 = *(const f16x8*)(A0 + ks * 32);
    const f16x8 Af1 = *(const f16x8*)(A1 + ks * 32);
#pragma unroll
    for (int nb = 0; nb < 16; ++nb) {
      const f16x8 Bf = *(const f16x8*)(Bbase + nb * 2048 + ks * 32);
      C0[nb] = __builtin_amdgcn_mfma_f32_16x16x32_f16(Af0, Bf, C0[nb], 0, 0, 0);
      C1[nb] = __builtin_amdgcn_mfma_f32_16x16x32_f16(Af1, Bf, C1[nb], 0, 0, 0);
    }
  }

  float colsum[16];
#pragma unroll
  for (int nb = 0; nb < 16; ++nb) colsum[nb] = 0.f;

#pragma unroll
  for (int half = 0; half < 2; ++half) {
    f32x4* C = half ? C1 : C0;
    const int bt = bt0 + half;
    float mx[4], sum[4];
#pragma unroll
    for (int r = 0; r < 4; ++r) mx[r] = C[0][r];
#pragma unroll
    for (int nb = 1; nb < 16; ++nb)
#pragma unroll
      for (int r = 0; r < 4; ++r) mx[r] = fmaxf(mx[r], C[nb][r]);
#pragma unroll
    for (int r = 0; r < 4; ++r) {
      mx[r] = fmaxf(mx[r], __shfl_xor(mx[r], 1, 16));
      mx[r] = fmaxf(mx[r], __shfl_xor(mx[r], 2, 16));
      mx[r] = fmaxf(mx[r], __shfl_xor(mx[r], 4, 16));
      mx[r] = fmaxf(mx[r], __shfl_xor(mx[r], 8, 16));
      sum[r] = 0.f;
    }
#pragma unroll
    for (int nb = 0; nb < 16; ++nb)
#pragma unroll
      for (int r = 0; r < 4; ++r) {
        const float e = __expf(C[nb][r] - mx[r]);
        C[nb][r] = e;
        sum[r] += e;
      }
#pragma unroll
    for (int r = 0; r < 4; ++r) {
      sum[r] += __shfl_xor(sum[r], 1, 16);
      sum[r] += __shfl_xor(sum[r], 2, 16);
      sum[r] += __shfl_xor(sum[r], 4, 16);
      sum[r] += __shfl_xor(sum[r], 8, 16);
      sum[r] = 1.f / sum[r];
    }
    _Float16* slot = sm[wave];
#pragma unroll
    for (int nb = 0; nb < 16; ++nb) {
#pragma unroll
      for (int r = 0; r < 4; ++r) {
        const float v = C[nb][r] * sum[r];
        colsum[nb] += v;
        // nb^q swizzle at 16-elem (32B) granularity: banks ((nb^q)%4)*8+c/2
        // cover all 32 -> conflict-free (was 4-way).
        slot[(q * 4 + r) * 256 + ((nb ^ q) * 16) + c] = (_Float16)v;
      }
    }
    const int l2 = lane & 31, rh = lane >> 5;
    _Float16* Pg = PiF + ((size_t)(bt * 16) * 256 + n) * 256;
#pragma unroll
    for (int i = 0; i < 8; ++i) {
      const int row = i * 2 + rh;
      const int g = l2 >> 1;  // logical 16-elem granule
      const uint4 v = *(const uint4*)(slot + row * 256 +
                                      ((g ^ (row >> 2)) * 16) + (l2 & 1) * 8);
      *(uint4*)(Pg + (size_t)row * 65536 + l2 * 8) = v;
    }
  }
#pragma unroll
  for (int nb = 0; nb < 16; ++nb) {
    colsum[nb] += __shfl_xor(colsum[nb], 16);
    colsum[nb] += __shfl_xor(colsum[nb], 32);
  }
  // block-level colsum reduction: 8 waves -> 1 set of 256 atomics per block
  __syncthreads();                 // all slot reads done; safe to repurpose
  float* red = (float*)sm;         // 8 KB of the slot buffer
  if (lane < 16) {
#pragma unroll
    for (int nb = 0; nb < 16; ++nb)
      red[wave * 256 + nb * 16 + lane] = colsum[nb];
  }
  __syncthreads();
  if (tid < 256) {
    float s = 0.f;
#pragma unroll
    for (int ww = 0; ww < 8; ++ww) s += red[ww * 256 + tid];
    atomicAdd(pimpart + n * 256 + tid, s);
  }
}

// ---------------- SEIR RK4 simulation — r8 structure, 2-WAY TEMPORAL SPLIT -
// r17 data: gather G=19.7us, per-week W=10.8us. 2-way split (84us halves)
// keeps parts below the sim ceiling while reclaiming the 4-way split's +2G.
__global__ __launch_bounds__(256, 2) void k_sim_part(
    const _Float16* __restrict__ PiF, const float* __restrict__ betaW,
    const float* __restrict__ sigmaW, const float* __restrict__ gammaW,
    float* __restrict__ SW, float* __restrict__ EW, float* __restrict__ IW,
    const float* __restrict__ stats, const float* __restrict__ pimpart,
    float* __restrict__ out, int wk0, int nwk, int do_finalize) {
  const int b = blockIdx.x;
  const int tid = threadIdx.x;

  if (do_finalize) {  // fused k_finalize: means of stats + Pi (part a only)
    const int g = b * 256 + tid;
    if (g < 66304) {
      const float inv = 1.f / 512.f;
      if (g < 768) out[3145728 + g] = stats[g] * inv;
      else out[3146496 + (g - 768)] = pimpart[g - 768] * inv;
    }
  }

  const int w = tid >> 6, lane = tid & 63;
  const int q = lane >> 4, c = lane & 15;
  const int mown = (4 * w + q) * 16 + c;

  __shared__ __align__(16) _Float16 Ib[2][256];

  f16x8 Bf[4][8];
  {
    const _Float16* P = PiF + (size_t)b * 65536 + (size_t)(q * 8) * 256 + c;
#pragma unroll
    for (int i = 0; i < 4; ++i) {
#pragma unroll
      for (int t = 0; t < 8; ++t) {
        const _Float16* src = P + (size_t)(t * 32) * 256 + (4 * w + i) * 16;
        f16x8 v;
#pragma unroll
        for (int j = 0; j < 8; ++j) v[j] = src[(size_t)j * 256];
        Bf[i][t] = v;
      }
    }
  }

  const int base = b * 256 + mown;
  const float bet = betaW[base], sig = sigmaW[base], gam = gammaW[base];
  float S = SW[base], E = EW[base], I = IW[base];

  int p = 0;
  auto grads = [&](float Ss, float Es, float Is, float& dS, float& dE, float& dI) {
    Ib[p][mown] = (_Float16)Is;
    __syncthreads();
    const f16x8* ia = (const f16x8*)Ib[p];
    p ^= 1;
    f32x4 C[4];
#pragma unroll
    for (int i = 0; i < 4; ++i) C[i] = f32x4{0.f, 0.f, 0.f, 0.f};
#pragma unroll
    for (int t = 0; t < 8; ++t) {
      const f16x8 A = ia[t * 4 + q];  // element offset t*32 + q*8
#pragma unroll
      for (int i = 0; i < 4; ++i)
        C[i] = __builtin_amdgcn_mfma_f32_16x16x32_f16(A, Bf[i][t], C[i], 0, 0, 0);
    }
    // force for m = (4w+q)*16+c lives in C[q] (all rows identical)
    const float force = (q & 2) ? ((q & 1) ? C[3][0] : C[2][0])
                                : ((q & 1) ? C[1][0] : C[0][0]);
    const float ninf = bet * Ss * force;
    const float sE = sig * Es;
    dS = -ninf;
    dE = ninf - sE;
    dI = sE - gam * Is;
  };

  float* outI = out + (size_t)b * (12 * 256) + mown;
  float* outE = outI + 1572864;
  const float c6 = 0.25f / 6.f;

  for (int wk = wk0; wk < wk0 + nwk; ++wk) {
    for (int st = 0; st < 4; ++st) {
      float d1S, d1E, d1I, d2S, d2E, d2I, d3S, d3E, d3I, d4S, d4E, d4I;
      grads(S, E, I, d1S, d1E, d1I);
      grads(S + 0.125f * d1S, E + 0.125f * d1E, I + 0.125f * d1I, d2S, d2E, d2I);
      grads(S + 0.125f * d2S, E + 0.125f * d2E, I + 0.125f * d2I, d3S, d3E, d3I);
      grads(S + 0.25f * d3S, E + 0.25f * d3E, I + 0.25f * d3I, d4S, d4E, d4I);
      S = fminf(fmaxf(S + c6 * (d1S + 2.f * d2S + 2.f * d3S + d4S), 0.f), 1.f);
      E = fminf(fmaxf(E + c6 * (d1E + 2.f * d2E + 2.f * d3E + d4E), 0.f), 1.f);
      I = fminf(fmaxf(I + c6 * (d1I + 2.f * d2I + 2.f * d3I + d4I), 0.f), 1.f);
    }
    outI[wk * 256] = I;
    outE[wk * 256] = E;
  }

  // persist exact f32 state for the next part (harmless in the last part)
  SW[base] = S; EW[base] = E; IW[base] = I;
}

// ---------------- launch ---------------------------------------------------
extern "C" void kernel_launch(void* const* d_in, const int* in_sizes, int n_in,
                              void* d_out, int out_size, void* d_ws, size_t ws_size,
                              hipStream_t stream) {
  const float* x_hist = (const float*)d_in[0];
  const float* cnn    = (const float*)d_in[1];
  const float* W1     = (const float*)d_in[2];
  const float* b1     = (const float*)d_in[3];
  const float* W2     = (const float*)d_in[4];
  const float* b2     = (const float*)d_in[5];
  const float* M1     = (const float*)d_in[6];
  const float* mb1    = (const float*)d_in[7];
  const float* M2     = (const float*)d_in[8];
  const float* mb2    = (const float*)d_in[9];
  float* out = (float*)d_out;

  char* w = (char*)d_ws;
  _Float16* M2T     = (_Float16*)(w + 0);         // 16,777,216
  _Float16* hmf     = (_Float16*)(w + 16777216);  //    131,072
  float*    betaW   = (float*)(w + 16908288);     //    524,288 each
  float*    sigmaW  = (float*)(w + 17432576);
  float*    gammaW  = (float*)(w + 17956864);
  float*    S0W     = (float*)(w + 18481152);
  float*    E0W     = (float*)(w + 19005440);
  float*    I0W     = (float*)(w + 19529728);
  float*    pimpart = (float*)(w + 20054016);     //    262,144
  float*    stats   = (float*)(w + 20316160);     //      4,096 (768 used)
  _Float16* PiF     = (_Float16*)(w + 20320256);  // 67,108,864 (end 87.4MB)
  // hpart/h alias the PiF region (dead before k_mobility2 writes PiF)
  float*    hpart   = (float*)(w + 20320256);     //  8,388,608
  float*    h       = (float*)(w + 28708864);     //    262,144

  hipMemsetAsync(pimpart, 0, 266240, stream);  // pimpart + stats
  k_paramnet1<<<dim3(32, 16), 256, 0, stream>>>(x_hist, W1, hpart);
  k_paramnet2<<<256, 256, 0, stream>>>(hpart, b1, h);
  k_params_state<<<512, 256, 0, stream>>>(h, W2, b2, x_hist, betaW, sigmaW,
                                          gammaW, S0W, E0W, I0W, stats);
  k_cvtM2<<<256, 256, 0, stream>>>(M2, M2T, cnn, M1, mb1, hmf);
  k_mobility2<<<dim3(256, 2), 512, 0, stream>>>(hmf, M2T, mb2, PiF, pimpart);
  k_sim_part<<<512, 256, 0, stream>>>(PiF, betaW, sigmaW, gammaW, S0W, E0W,
                                      I0W, stats, pimpart, out, 0, 6, 1);
  k_sim_part<<<512, 256, 0, stream>>>(PiF, betaW, sigmaW, gammaW, S0W, E0W,
                                      I0W, stats, pimpart, out, 6, 6, 0);
}